// Round 1
// baseline (660.644 us; speedup 1.0000x reference)
//
#include <hip/hip_runtime.h>
#include <cstdint>
#include <cstddef>

// Problem constants (B=2, S=2048 -> T=4096 tokens)
#define TT 4096
#define DD 1024
#define MM 2048
#define EE 8
#define NPAIR 8192   // TT * top_k(2)

typedef unsigned short u16;
typedef __bf16 bf16x8 __attribute__((ext_vector_type(8)));
typedef float f32x4 __attribute__((ext_vector_type(4)));
typedef __attribute__((address_space(3))) void* lds_vp;
typedef __attribute__((address_space(1))) const void* gbl_cvp;

__device__ __forceinline__ void async16(u16* l, const u16* g) {
  __builtin_amdgcn_global_load_lds((gbl_cvp)(const void*)g, (lds_vp)(void*)l, 16, 0, 0);
}

__device__ __forceinline__ u16 f2bf(float f) {
  uint32_t u = __builtin_bit_cast(uint32_t, f);
  u += 0x7fffu + ((u >> 16) & 1u);   // RNE
  return (u16)(u >> 16);
}
__device__ __forceinline__ float bf2f(u16 h) {
  uint32_t u = ((uint32_t)h) << 16;
  return __builtin_bit_cast(float, u);
}

// ---------------- router: logits -> softmax -> top2 -> renorm ----------------
// one wave per token; 4 waves/block
__global__ void router_kernel(const float* __restrict__ X, const float* __restrict__ Wr,
                              int* __restrict__ tok_idx, float* __restrict__ wpair,
                              int* __restrict__ counts) {
  int wave = threadIdx.x >> 6;
  int lane = threadIdx.x & 63;
  int t = blockIdx.x * 4 + wave;
  if (t >= TT) return;
  const float* xr = X + (size_t)t * DD;
  float acc[EE];
#pragma unroll
  for (int e = 0; e < EE; e++) acc[e] = 0.f;
  for (int d = lane; d < DD; d += 64) {
    float xv = xr[d];
    const float* wr = Wr + (size_t)d * EE;
#pragma unroll
    for (int e = 0; e < EE; e++) acc[e] += xv * wr[e];
  }
#pragma unroll
  for (int e = 0; e < EE; e++) {
    float v = acc[e];
    for (int off = 32; off > 0; off >>= 1) v += __shfl_down(v, off);
    acc[e] = v;
  }
  if (lane == 0) {
    float mx = acc[0];
#pragma unroll
    for (int e = 1; e < EE; e++) mx = fmaxf(mx, acc[e]);
    float p[EE], s = 0.f;
#pragma unroll
    for (int e = 0; e < EE; e++) { p[e] = __expf(acc[e] - mx); s += p[e]; }
    float inv = 1.f / s;
#pragma unroll
    for (int e = 0; e < EE; e++) p[e] *= inv;
    int i0 = 0;
#pragma unroll
    for (int e = 1; e < EE; e++) if (p[e] > p[i0]) i0 = e;
    int i1 = (i0 == 0) ? 1 : 0;
#pragma unroll
    for (int e = 0; e < EE; e++) if (e != i0 && p[e] > p[i1]) i1 = e;
    float denom = p[i0] + p[i1] + 1e-8f;
    tok_idx[t * 2 + 0] = i0;
    tok_idx[t * 2 + 1] = i1;
    wpair[t * 2 + 0] = p[i0] / denom;
    wpair[t * 2 + 1] = p[i1] / denom;
    atomicAdd(&counts[i0], 1);
    atomicAdd(&counts[i1], 1);
  }
}

__global__ void offsets_kernel(const int* __restrict__ counts, int* __restrict__ offsets) {
  if (threadIdx.x == 0) {
    int s = 0;
    for (int e = 0; e < EE; e++) { offsets[e] = s; s += counts[e]; }
    offsets[EE] = s;
  }
}

__global__ void scatter_kernel(const int* __restrict__ tok_idx, const int* __restrict__ offsets,
                               int* __restrict__ cursors, int* __restrict__ bucket) {
  int t = blockIdx.x * 256 + threadIdx.x;
  if (t >= TT) return;
#pragma unroll
  for (int k = 0; k < 2; k++) {
    int e = tok_idx[t * 2 + k];
    int pos = atomicAdd(&cursors[e], 1);
    bucket[offsets[e] + pos] = t * 2 + k;
  }
}

// ---------------- fp32 -> bf16 convert of residual ----------------
__global__ void cvtx_kernel(const float* __restrict__ X, u16* __restrict__ Xbf) {
  int i = blockIdx.x * 256 + threadIdx.x;   // over TT*DD/4 float4s
  float4 v = ((const float4*)X)[i];
  ushort4 o;
  o.x = f2bf(v.x); o.y = f2bf(v.y); o.z = f2bf(v.z); o.w = f2bf(v.w);
  ((ushort4*)Xbf)[i] = o;
}

// ---------------- transpose+convert: in [E][R][C] f32 -> out [E][C][R] bf16 ----------------
__global__ void transpose_cvt(const float* __restrict__ in, u16* __restrict__ out, int R, int C) {
  __shared__ float tile[32][33];
  int e = blockIdx.z;
  const float* I = in + (size_t)e * R * C;
  u16* O = out + (size_t)e * R * C;
  int c0 = blockIdx.x * 32, r0 = blockIdx.y * 32;
  for (int i = threadIdx.y; i < 32; i += 8)
    tile[i][threadIdx.x] = I[(size_t)(r0 + i) * C + c0 + threadIdx.x];
  __syncthreads();
  for (int i = threadIdx.y; i < 32; i += 8)
    O[(size_t)(c0 + i) * R + r0 + threadIdx.x] = f2bf(tile[threadIdx.x][i]);
}

// ---------------- grouped MFMA GEMM ----------------
// MODE 0: U = X*Wu + b_up            -> Hws (bf16)
// MODE 1: H = silu(X*Wg + b_gate)*U  -> Hws (bf16, in place over U)
// MODE 2: Ypart[pair] = w*(H*Wo + b_out)  (f32)
// A rows live in bucket order; tiles never cross expert boundaries.
template <int MODE>
__global__ __launch_bounds__(256)
void moe_gemm(const u16* __restrict__ Aglob, const u16* __restrict__ Wt,
              const float* __restrict__ bias, u16* __restrict__ Hws,
              float* __restrict__ Ypart, const int* __restrict__ offsets,
              const int* __restrict__ bucket, const float* __restrict__ wpair) {
  constexpr int K = (MODE == 2) ? MM : DD;
  constexpr int N = (MODE == 2) ? DD : MM;

  // map blockIdx.x -> (expert, row tile)
  int x = blockIdx.x;
  int expert = -1, row0 = 0, rows = 0;
#pragma unroll 1
  for (int e = 0; e < EE; e++) {
    int o0 = offsets[e], o1 = offsets[e + 1];
    int nt = (o1 - o0 + 127) >> 7;
    if (x < nt) { expert = e; row0 = o0 + (x << 7); rows = min(128, o1 - row0); break; }
    x -= nt;
  }
  if (expert < 0) return;
  int n0 = blockIdx.y * 128;

  __shared__ u16 Alds[128 * 32];
  __shared__ u16 Blds[128 * 32];

  int tid = threadIdx.x;
  int wave = tid >> 6, lane = tid & 63;
  int wm = wave >> 1, wn = wave & 1;
  int quad = lane >> 4, l15 = lane & 15;

  // A staging rows for this lane (two 16-row groups per wave)
  long arow0, arow1;
  {
    int r0l = wave * 32 + (lane >> 2);
    int r1l = r0l + 16;
    int rr0 = min(r0l, rows - 1);
    int rr1 = min(r1l, rows - 1);
    if (MODE == 2) {
      arow0 = (long)(row0 + rr0) * K;
      arow1 = (long)(row0 + rr1) * K;
    } else {
      arow0 = (long)(bucket[row0 + rr0] >> 1) * K;
      arow1 = (long)(bucket[row0 + rr1] >> 1) * K;
    }
  }
  const u16* Wbase = Wt + (size_t)expert * N * K + (size_t)n0 * K;
  int brow = wave * 32 + (lane >> 2);
  int lchunk = (lane & 3) * 8;   // element offset of this lane's 16B within a 32-elem row

  f32x4 acc[4][4];
#pragma unroll
  for (int i = 0; i < 4; i++)
#pragma unroll
    for (int j = 0; j < 4; j++) acc[i][j] = (f32x4){0.f, 0.f, 0.f, 0.f};

  for (int k0 = 0; k0 < K; k0 += 32) {
    async16(&Alds[(wave * 32) * 32], Aglob + arow0 + k0 + lchunk);
    async16(&Alds[(wave * 32 + 16) * 32], Aglob + arow1 + k0 + lchunk);
    async16(&Blds[(wave * 32) * 32], Wbase + (long)brow * K + k0 + lchunk);
    async16(&Blds[(wave * 32 + 16) * 32], Wbase + (long)(brow + 16) * K + k0 + lchunk);
    __syncthreads();
    bf16x8 af[4], bfr[4];
#pragma unroll
    for (int i = 0; i < 4; i++) {
      af[i]  = *(const bf16x8*)&Alds[(wm * 64 + i * 16 + l15) * 32 + quad * 8];
      bfr[i] = *(const bf16x8*)&Blds[(wn * 64 + i * 16 + l15) * 32 + quad * 8];
    }
#pragma unroll
    for (int i = 0; i < 4; i++)
#pragma unroll
      for (int j = 0; j < 4; j++)
        acc[i][j] = __builtin_amdgcn_mfma_f32_16x16x32_bf16(af[i], bfr[j], acc[i][j], 0, 0, 0);
    __syncthreads();
  }

  // epilogue: C/D layout col = lane&15, row = quad*4 + r
#pragma unroll
  for (int i = 0; i < 4; i++) {
    int lrb = wm * 64 + i * 16 + quad * 4;
#pragma unroll
    for (int j = 0; j < 4; j++) {
      int gc = n0 + wn * 64 + j * 16 + l15;
      float bv = bias[expert * N + gc];
#pragma unroll
      for (int r = 0; r < 4; r++) {
        int lr = lrb + r;
        if (lr < rows) {
          int grow = row0 + lr;
          float v = acc[i][j][r] + bv;
          if (MODE == 0) {
            Hws[(size_t)grow * MM + gc] = f2bf(v);
          } else if (MODE == 1) {
            float u = bf2f(Hws[(size_t)grow * MM + gc]);
            float sg = v / (1.f + __expf(-v));
            Hws[(size_t)grow * MM + gc] = f2bf(sg * u);
          } else {
            int p = bucket[grow];
            float w = wpair[p];
            Ypart[(size_t)p * DD + gc] = w * v;
          }
        }
      }
    }
  }
}

// ---------------- combine the two expert contributions per token ----------------
__global__ void combine_kernel(const float* __restrict__ Ypart, float* __restrict__ out) {
  int i = blockIdx.x * 256 + threadIdx.x;   // over TT*DD/4
  int t = i >> 8;          // DD/4 = 256 float4 per token
  int c4 = i & 255;
  const float4* y0 = (const float4*)(Ypart + (size_t)(2 * t) * DD) + c4;
  const float4* y1 = (const float4*)(Ypart + (size_t)(2 * t + 1) * DD) + c4;
  float4 a = *y0, b = *y1;
  float4 o;
  o.x = a.x + b.x; o.y = a.y + b.y; o.z = a.z + b.z; o.w = a.w + b.w;
  ((float4*)out)[i] = o;
}

extern "C" void kernel_launch(void* const* d_in, const int* in_sizes, int n_in,
                              void* d_out, int out_size, void* d_ws, size_t ws_size,
                              hipStream_t stream) {
  const float* residual = (const float*)d_in[0];
  const float* W_router = (const float*)d_in[1];
  const float* W_gate   = (const float*)d_in[2];
  const float* b_gate   = (const float*)d_in[3];
  const float* W_up     = (const float*)d_in[4];
  const float* b_up     = (const float*)d_in[5];
  const float* W_out    = (const float*)d_in[6];
  const float* b_out    = (const float*)d_in[7];
  float* out = (float*)d_out;

  char* ws = (char*)d_ws;
  int*   tok_idx = (int*)(ws + 0);                       // 8192 ints
  float* wpair   = (float*)(ws + 32768);                 // 8192 floats
  int*   ctrl    = (int*)(ws + 65536);                   // counts[8] | offsets[9] | cursors[8]
  int*   counts  = ctrl;
  int*   offsets = ctrl + 8;
  int*   cursors = ctrl + 20;
  int*   bucket  = (int*)(ws + 65536 + 512);             // 8192 ints
  u16*   Xbf  = (u16*)(ws + 131072);                                     // 8 MB
  u16*   WtG  = Xbf + (size_t)TT * DD;                                   // 32 MB  [E][M][D]
  u16*   WtU  = WtG + (size_t)EE * MM * DD;                              // 32 MB  [E][M][D]
  u16*   WtO  = WtU + (size_t)EE * MM * DD;                              // 32 MB  [E][D][M]
  u16*   Hws  = WtO + (size_t)EE * DD * MM;                              // 32 MB  [8192][M]
  float* Ypart = (float*)(Hws + (size_t)NPAIR * MM);                     // 32 MB  [8192][D]

  hipMemsetAsync(ctrl, 0, 512, stream);

  // residual -> bf16
  cvtx_kernel<<<dim3(TT * DD / 4 / 256), dim3(256), 0, stream>>>(residual, Xbf);
  // weight transposes (K-contiguous bf16)
  transpose_cvt<<<dim3(MM / 32, DD / 32, EE), dim3(32, 8), 0, stream>>>(W_gate, WtG, DD, MM);
  transpose_cvt<<<dim3(MM / 32, DD / 32, EE), dim3(32, 8), 0, stream>>>(W_up,   WtU, DD, MM);
  transpose_cvt<<<dim3(DD / 32, MM / 32, EE), dim3(32, 8), 0, stream>>>(W_out,  WtO, MM, DD);
  // routing
  router_kernel<<<dim3(TT / 4), dim3(256), 0, stream>>>(residual, W_router, tok_idx, wpair, counts);
  offsets_kernel<<<dim3(1), dim3(64), 0, stream>>>(counts, offsets);
  scatter_kernel<<<dim3(TT / 256), dim3(256), 0, stream>>>(tok_idx, offsets, cursors, bucket);
  // grouped GEMMs: max row tiles = 64 + 8 = 72
  moe_gemm<0><<<dim3(72, MM / 128), dim3(256), 0, stream>>>(Xbf, WtU, b_up,  Hws, Ypart, offsets, bucket, wpair);
  moe_gemm<1><<<dim3(72, MM / 128), dim3(256), 0, stream>>>(Xbf, WtG, b_gate, Hws, Ypart, offsets, bucket, wpair);
  moe_gemm<2><<<dim3(72, DD / 128), dim3(256), 0, stream>>>(Hws, WtO, b_out, Hws, Ypart, offsets, bucket, wpair);
  // combine
  combine_kernel<<<dim3(TT * DD / 4 / 256), dim3(256), 0, stream>>>(Ypart, out);
}

// Round 2
// 529.049 us; speedup vs baseline: 1.2487x; 1.2487x over previous
//
#include <hip/hip_runtime.h>
#include <cstdint>
#include <cstddef>

// Problem constants (B=2, S=2048 -> T=4096 tokens)
#define TT 4096
#define DD 1024
#define MM 2048
#define EE 8
#define NPAIR 8192   // TT * top_k(2)

typedef unsigned short u16;
typedef __bf16 bf16x8 __attribute__((ext_vector_type(8)));
typedef float f32x4 __attribute__((ext_vector_type(4)));
typedef __attribute__((address_space(3))) void* lds_vp;
typedef __attribute__((address_space(1))) const void* gbl_cvp;

__device__ __forceinline__ void async16(u16* l, const u16* g) {
  __builtin_amdgcn_global_load_lds((gbl_cvp)(const void*)g, (lds_vp)(void*)l, 16, 0, 0);
}

__device__ __forceinline__ u16 f2bf(float f) {
  uint32_t u = __builtin_bit_cast(uint32_t, f);
  u += 0x7fffu + ((u >> 16) & 1u);   // RNE
  return (u16)(u >> 16);
}
__device__ __forceinline__ float bf2f(u16 h) {
  uint32_t u = ((uint32_t)h) << 16;
  return __builtin_bit_cast(float, u);
}

// ---------------- router: logits -> softmax -> top2 -> renorm ----------------
// one wave per token; 4 waves/block; NO device atomics (they serialized R1 at 105us)
__global__ void router_kernel(const float* __restrict__ X, const float* __restrict__ Wr,
                              int* __restrict__ tok_idx, float* __restrict__ wpair) {
  int wave = threadIdx.x >> 6;
  int lane = threadIdx.x & 63;
  int t = blockIdx.x * 4 + wave;
  const float4* x4 = (const float4*)(X + (size_t)t * DD);
  float acc[EE];
#pragma unroll
  for (int e = 0; e < EE; e++) acc[e] = 0.f;
#pragma unroll
  for (int i = 0; i < 4; i++) {
    float4 xv = x4[i * 64 + lane];
    const float4* wr4 = (const float4*)(Wr + (size_t)(i * 256 + lane * 4) * EE);
    float xs[4] = {xv.x, xv.y, xv.z, xv.w};
#pragma unroll
    for (int c = 0; c < 4; c++) {
      float4 wa = wr4[c * 2 + 0];
      float4 wb = wr4[c * 2 + 1];
      acc[0] += xs[c] * wa.x; acc[1] += xs[c] * wa.y;
      acc[2] += xs[c] * wa.z; acc[3] += xs[c] * wa.w;
      acc[4] += xs[c] * wb.x; acc[5] += xs[c] * wb.y;
      acc[6] += xs[c] * wb.z; acc[7] += xs[c] * wb.w;
    }
  }
#pragma unroll
  for (int off = 32; off > 0; off >>= 1)
#pragma unroll
    for (int e = 0; e < EE; e++) acc[e] += __shfl_xor(acc[e], off);
  if (lane == 0) {
    float mx = acc[0];
#pragma unroll
    for (int e = 1; e < EE; e++) mx = fmaxf(mx, acc[e]);
    float p[EE], s = 0.f;
#pragma unroll
    for (int e = 0; e < EE; e++) { p[e] = __expf(acc[e] - mx); s += p[e]; }
    float inv = 1.f / s;
#pragma unroll
    for (int e = 0; e < EE; e++) p[e] *= inv;
    int i0 = 0;
#pragma unroll
    for (int e = 1; e < EE; e++) if (p[e] > p[i0]) i0 = e;
    int i1 = (i0 == 0) ? 1 : 0;
#pragma unroll
    for (int e = 0; e < EE; e++) if (e != i0 && p[e] > p[i1]) i1 = e;
    float denom = p[i0] + p[i1] + 1e-8f;
    tok_idx[t * 2 + 0] = i0;
    tok_idx[t * 2 + 1] = i1;
    wpair[t * 2 + 0] = p[i0] / denom;
    wpair[t * 2 + 1] = p[i1] / denom;
  }
}

// ---------------- single-block bucketing via LDS atomics ----------------
// counts -> offsets -> scatter, all in one block (LDS atomics are ~cycles, not ~100ns)
__global__ void bucket_kernel(const int* __restrict__ tok_idx, int* __restrict__ offsets,
                              int* __restrict__ bucket) {
  __shared__ int lcnt[EE];
  __shared__ int lcur[EE];
  int tid = threadIdx.x;   // 1024 threads
  if (tid < EE) lcnt[tid] = 0;
  __syncthreads();
  for (int i = tid; i < NPAIR; i += 1024) atomicAdd(&lcnt[tok_idx[i]], 1);
  __syncthreads();
  if (tid == 0) {
    int s = 0;
    for (int e = 0; e < EE; e++) {
      offsets[e] = s;
      lcur[e] = s;
      s += lcnt[e];
    }
    offsets[EE] = s;
  }
  __syncthreads();
  for (int i = tid; i < NPAIR; i += 1024) {
    int e = tok_idx[i];
    int pos = atomicAdd(&lcur[e], 1);
    bucket[pos] = i;
  }
}

// ---------------- fp32 -> bf16 convert of residual ----------------
__global__ void cvtx_kernel(const float* __restrict__ X, u16* __restrict__ Xbf) {
  int i = blockIdx.x * 256 + threadIdx.x;   // over TT*DD/4 float4s
  float4 v = ((const float4*)X)[i];
  ushort4 o;
  o.x = f2bf(v.x); o.y = f2bf(v.y); o.z = f2bf(v.z); o.w = f2bf(v.w);
  ((ushort4*)Xbf)[i] = o;
}

// ---------------- transpose+convert: in [E][R][C] f32 -> out [E][C][R] bf16 ----------------
__global__ void transpose_cvt(const float* __restrict__ in, u16* __restrict__ out, int R, int C) {
  __shared__ float tile[32][33];
  int e = blockIdx.z;
  const float* I = in + (size_t)e * R * C;
  u16* O = out + (size_t)e * R * C;
  int c0 = blockIdx.x * 32, r0 = blockIdx.y * 32;
  for (int i = threadIdx.y; i < 32; i += 8)
    tile[i][threadIdx.x] = I[(size_t)(r0 + i) * C + c0 + threadIdx.x];
  __syncthreads();
  for (int i = threadIdx.y; i < 32; i += 8)
    O[(size_t)(c0 + i) * R + r0 + threadIdx.x] = f2bf(tile[threadIdx.x][i]);
}

// ---------------- grouped MFMA GEMM ----------------
// MODE 0: U = X*Wu + b_up            -> Hws (bf16)
// MODE 1: H = silu(X*Wg + b_gate)*U  -> Hws (bf16, in place over U)
// MODE 2: Ypart[pair] = w*(H*Wo + b_out)  (f32)
// A rows live in bucket order; tiles never cross expert boundaries.
template <int MODE>
__global__ __launch_bounds__(256)
void moe_gemm(const u16* __restrict__ Aglob, const u16* __restrict__ Wt,
              const float* __restrict__ bias, u16* __restrict__ Hws,
              float* __restrict__ Ypart, const int* __restrict__ offsets,
              const int* __restrict__ bucket, const float* __restrict__ wpair) {
  constexpr int K = (MODE == 2) ? MM : DD;
  constexpr int N = (MODE == 2) ? DD : MM;

  // map blockIdx.x -> (expert, row tile)
  int x = blockIdx.x;
  int expert = -1, row0 = 0, rows = 0;
#pragma unroll 1
  for (int e = 0; e < EE; e++) {
    int o0 = offsets[e], o1 = offsets[e + 1];
    int nt = (o1 - o0 + 127) >> 7;
    if (x < nt) { expert = e; row0 = o0 + (x << 7); rows = min(128, o1 - row0); break; }
    x -= nt;
  }
  if (expert < 0) return;
  int n0 = blockIdx.y * 128;

  __shared__ u16 Alds[128 * 32];
  __shared__ u16 Blds[128 * 32];

  int tid = threadIdx.x;
  int wave = tid >> 6, lane = tid & 63;
  int wm = wave >> 1, wn = wave & 1;
  int quad = lane >> 4, l15 = lane & 15;

  // A staging rows for this lane (two 16-row groups per wave)
  long arow0, arow1;
  {
    int r0l = wave * 32 + (lane >> 2);
    int r1l = r0l + 16;
    int rr0 = min(r0l, rows - 1);
    int rr1 = min(r1l, rows - 1);
    if (MODE == 2) {
      arow0 = (long)(row0 + rr0) * K;
      arow1 = (long)(row0 + rr1) * K;
    } else {
      arow0 = (long)(bucket[row0 + rr0] >> 1) * K;
      arow1 = (long)(bucket[row0 + rr1] >> 1) * K;
    }
  }
  const u16* Wbase = Wt + (size_t)expert * N * K + (size_t)n0 * K;
  int brow = wave * 32 + (lane >> 2);
  int lchunk = (lane & 3) * 8;   // element offset of this lane's 16B within a 32-elem row

  f32x4 acc[4][4];
#pragma unroll
  for (int i = 0; i < 4; i++)
#pragma unroll
    for (int j = 0; j < 4; j++) acc[i][j] = (f32x4){0.f, 0.f, 0.f, 0.f};

  for (int k0 = 0; k0 < K; k0 += 32) {
    async16(&Alds[(wave * 32) * 32], Aglob + arow0 + k0 + lchunk);
    async16(&Alds[(wave * 32 + 16) * 32], Aglob + arow1 + k0 + lchunk);
    async16(&Blds[(wave * 32) * 32], Wbase + (long)brow * K + k0 + lchunk);
    async16(&Blds[(wave * 32 + 16) * 32], Wbase + (long)(brow + 16) * K + k0 + lchunk);
    __syncthreads();
    bf16x8 af[4], bfr[4];
#pragma unroll
    for (int i = 0; i < 4; i++) {
      af[i]  = *(const bf16x8*)&Alds[(wm * 64 + i * 16 + l15) * 32 + quad * 8];
      bfr[i] = *(const bf16x8*)&Blds[(wn * 64 + i * 16 + l15) * 32 + quad * 8];
    }
#pragma unroll
    for (int i = 0; i < 4; i++)
#pragma unroll
      for (int j = 0; j < 4; j++)
        acc[i][j] = __builtin_amdgcn_mfma_f32_16x16x32_bf16(af[i], bfr[j], acc[i][j], 0, 0, 0);
    __syncthreads();
  }

  // epilogue: C/D layout col = lane&15, row = quad*4 + r
#pragma unroll
  for (int i = 0; i < 4; i++) {
    int lrb = wm * 64 + i * 16 + quad * 4;
#pragma unroll
    for (int j = 0; j < 4; j++) {
      int gc = n0 + wn * 64 + j * 16 + l15;
      float bv = bias[expert * N + gc];
#pragma unroll
      for (int r = 0; r < 4; r++) {
        int lr = lrb + r;
        if (lr < rows) {
          int grow = row0 + lr;
          float v = acc[i][j][r] + bv;
          if (MODE == 0) {
            Hws[(size_t)grow * MM + gc] = f2bf(v);
          } else if (MODE == 1) {
            float u = bf2f(Hws[(size_t)grow * MM + gc]);
            float sg = v / (1.f + __expf(-v));
            Hws[(size_t)grow * MM + gc] = f2bf(sg * u);
          } else {
            int p = bucket[grow];
            float w = wpair[p];
            Ypart[(size_t)p * DD + gc] = w * v;
          }
        }
      }
    }
  }
}

// ---------------- combine the two expert contributions per token ----------------
__global__ void combine_kernel(const float* __restrict__ Ypart, float* __restrict__ out) {
  int i = blockIdx.x * 256 + threadIdx.x;   // over TT*DD/4
  int t = i >> 8;          // DD/4 = 256 float4 per token
  int c4 = i & 255;
  const float4* y0 = (const float4*)(Ypart + (size_t)(2 * t) * DD) + c4;
  const float4* y1 = (const float4*)(Ypart + (size_t)(2 * t + 1) * DD) + c4;
  float4 a = *y0, b = *y1;
  float4 o;
  o.x = a.x + b.x; o.y = a.y + b.y; o.z = a.z + b.z; o.w = a.w + b.w;
  ((float4*)out)[i] = o;
}

extern "C" void kernel_launch(void* const* d_in, const int* in_sizes, int n_in,
                              void* d_out, int out_size, void* d_ws, size_t ws_size,
                              hipStream_t stream) {
  const float* residual = (const float*)d_in[0];
  const float* W_router = (const float*)d_in[1];
  const float* W_gate   = (const float*)d_in[2];
  const float* b_gate   = (const float*)d_in[3];
  const float* W_up     = (const float*)d_in[4];
  const float* b_up     = (const float*)d_in[5];
  const float* W_out    = (const float*)d_in[6];
  const float* b_out    = (const float*)d_in[7];
  float* out = (float*)d_out;

  char* ws = (char*)d_ws;
  int*   tok_idx = (int*)(ws + 0);                       // 8192 ints
  float* wpair   = (float*)(ws + 32768);                 // 8192 floats
  int*   offsets = (int*)(ws + 65536);                   // 9 ints
  int*   bucket  = (int*)(ws + 65536 + 512);             // 8192 ints
  u16*   Xbf  = (u16*)(ws + 131072);                                     // 8 MB
  u16*   WtG  = Xbf + (size_t)TT * DD;                                   // 32 MB  [E][M][D]
  u16*   WtU  = WtG + (size_t)EE * MM * DD;                              // 32 MB  [E][M][D]
  u16*   WtO  = WtU + (size_t)EE * MM * DD;                              // 32 MB  [E][D][M]
  u16*   Hws  = WtO + (size_t)EE * DD * MM;                              // 32 MB  [8192][M]
  float* Ypart = (float*)(Hws + (size_t)NPAIR * MM);                     // 32 MB  [8192][D]

  // residual -> bf16
  cvtx_kernel<<<dim3(TT * DD / 4 / 256), dim3(256), 0, stream>>>(residual, Xbf);
  // weight transposes (K-contiguous bf16)
  transpose_cvt<<<dim3(MM / 32, DD / 32, EE), dim3(32, 8), 0, stream>>>(W_gate, WtG, DD, MM);
  transpose_cvt<<<dim3(MM / 32, DD / 32, EE), dim3(32, 8), 0, stream>>>(W_up,   WtU, DD, MM);
  transpose_cvt<<<dim3(DD / 32, MM / 32, EE), dim3(32, 8), 0, stream>>>(W_out,  WtO, MM, DD);
  // routing (no device atomics)
  router_kernel<<<dim3(TT / 4), dim3(256), 0, stream>>>(residual, W_router, tok_idx, wpair);
  bucket_kernel<<<dim3(1), dim3(1024), 0, stream>>>(tok_idx, offsets, bucket);
  // grouped GEMMs: max row tiles = 64 + 8 = 72
  moe_gemm<0><<<dim3(72, MM / 128), dim3(256), 0, stream>>>(Xbf, WtU, b_up,  Hws, Ypart, offsets, bucket, wpair);
  moe_gemm<1><<<dim3(72, MM / 128), dim3(256), 0, stream>>>(Xbf, WtG, b_gate, Hws, Ypart, offsets, bucket, wpair);
  moe_gemm<2><<<dim3(72, DD / 128), dim3(256), 0, stream>>>(Hws, WtO, b_out, Hws, Ypart, offsets, bucket, wpair);
  // combine
  combine_kernel<<<dim3(TT * DD / 4 / 256), dim3(256), 0, stream>>>(Ypart, out);
}